// Round 8
// baseline (39.167 us; speedup 1.0000x reference)
//
#include <hip/hip_runtime.h>
#include <math.h>

#define TT 512
#define KP 4

typedef unsigned long long u64;

// LDS-only barrier: waits DS ops, leaves global stores in flight.
#define SYNCL() asm volatile("s_waitcnt lgkmcnt(0)\n\ts_barrier" ::: "memory")

// 512 blocks x 512 threads (8 waves). Block owns rows bn = 4*blk + r, r=0..3.
// Waves 0-3: compute team (wave r computes row r solo, no barriers inside).
// Waves 4-7: store team (wave 4+r stores row r: zero-region first, then data).
__global__ __launch_bounds__(512, 4) void periodicity_kernel(const float* __restrict__ x,
                                                             float* __restrict__ out) {
    const int blk  = blockIdx.x;     // 0..511
    const int tid  = threadIdx.x;    // 0..511
    const int lane = tid & 63;
    const int wid  = tid >> 6;       // 0..7

    __shared__ float2 tw[TT];                     // tw[m] = e^{-2*pi*i*m/512}
    __shared__ __align__(16) float rowl[4][TT];   // natural-order rows
    __shared__ float2 buf[4][TT];                 // per-row FFT buffers
    __shared__ u64    keys[4][256];
    __shared__ int    fin8s[4][8];
    __shared__ double candV8[4][8];
    __shared__ int    pstore[4][12];              // per[4], cyc[4], st[4]

    const size_t VOFF = (size_t)2048 * KP * 64 * 64;   // 33,554,432

    // ---- compute waves: issue scattered input loads early (hide latency) ----
    float v[8];
    if (wid < 4) {
        const int bn = blk * 4 + wid;
        const int b = bn >> 6, n = bn & 63;
        const float* xb = x + (size_t)b * (TT * 64) + n;
        #pragma unroll
        for (int q = 0; q < 8; ++q) v[q] = xb[(size_t)(lane + 64 * q) * 64];
    }

    // ---- twiddle table: all 512 threads, one sincosf each ----
    {
        float s, c;
        sincosf((float)(2.0 * M_PI / 512.0) * (float)tid, &s, &c);
        tw[tid] = make_float2(c, -s);
    }
    SYNCL();   // barrier 1: tw ready

    if (wid < 4) {
        // ================= compute team: wave owns row r = wid =================
        const int r  = wid;
        const int bn = blk * 4 + r;

        // row natural order + folded radix-2 first DIF stage (in registers)
        #pragma unroll
        for (int q = 0; q < 8; ++q) rowl[r][lane + 64 * q] = v[q];
        #pragma unroll
        for (int q = 0; q < 4; ++q) {
            const int t = lane + 64 * q;
            float sum = v[q] + v[q + 4], dif = v[q] - v[q + 4];
            float2 w = tw[t];
            buf[r][t]       = make_float2(sum, 0.f);
            buf[r][t + 256] = make_float2(dif * w.x, dif * w.y);
        }

        // 4 radix-4 DIF stages, 2 butterflies per lane (h = 0,1), no barriers
        #pragma unroll
        for (int stg = 0; stg < 4; ++stg) {
            #pragma unroll
            for (int h = 0; h < 2; ++h) {
                const int Q  = 64 >> (2 * stg);          // 64,16,4,1
                const int B4 = Q << 2;
                const int g  = lane >> (6 - 2 * stg);
                const int i  = lane & (Q - 1);
                float2* bb = &buf[r][h << 8];
                const int base = g * B4 + i;
                float2 x0 = bb[base],         x1 = bb[base + Q];
                float2 x2 = bb[base + 2 * Q], x3 = bb[base + 3 * Q];
                float2 A  = make_float2(x0.x + x2.x, x0.y + x2.y);
                float2 Bm = make_float2(x0.x - x2.x, x0.y - x2.y);
                float2 Cc = make_float2(x1.x + x3.x, x1.y + x3.y);
                float2 D  = make_float2(x1.x - x3.x, x1.y - x3.y);
                float2 y0 = make_float2(A.x + Cc.x, A.y + Cc.y);
                float2 y2 = make_float2(A.x - Cc.x, A.y - Cc.y);
                float2 y1 = make_float2(Bm.x + D.y, Bm.y - D.x);   // Bm - i*D
                float2 y3 = make_float2(Bm.x - D.y, Bm.y + D.x);   // Bm + i*D
                const int m = i << (1 + 2 * stg);
                float2 t1 = tw[m], t2 = tw[2 * m], t3 = tw[3 * m];
                bb[base]         = y0;
                bb[base + Q]     = make_float2(y1.x * t1.x - y1.y * t1.y, y1.x * t1.y + y1.y * t1.x);
                bb[base + 2 * Q] = make_float2(y2.x * t2.x - y2.y * t2.y, y2.x * t2.y + y2.y * t2.x);
                bb[base + 3 * Q] = make_float2(y3.x * t3.x - y3.y * t3.y, y3.x * t3.y + y3.y * t3.x);
            }
        }

        // scatter |X|^2 into packed keys (base-4 digit-reversed positions)
        #pragma unroll
        for (int q = 0; q < 8; ++q) {
            const int pos = lane + 64 * q;
            const int p = pos & 255, h = pos >> 8;
            const int kp = ((p & 3) << 6) | (((p >> 2) & 3) << 4) | (((p >> 4) & 3) << 2) | ((p >> 6) & 3);
            const int f = 2 * kp + h;
            if (f >= 1 && f <= 256) {
                float2 vv = buf[r][pos];
                float mag = vv.x * vv.x + vv.y * vv.y;
                keys[r][f - 1] = ((u64)__float_as_uint(mag) << 32) | (u64)(255 - (f - 1));
            }
        }

        // in-wave top-8 of 256 keys (value desc, bin asc)
        int   fbin[8];
        float cmag[8];
        {
            u64 k0 = keys[r][lane * 4 + 0];
            u64 k1 = keys[r][lane * 4 + 1];
            u64 k2 = keys[r][lane * 4 + 2];
            u64 k3 = keys[r][lane * 4 + 3];
            #define CSWAP(a, b) { if (a < b) { u64 _t = a; a = b; b = _t; } }
            CSWAP(k0, k1) CSWAP(k2, k3) CSWAP(k0, k2) CSWAP(k1, k3) CSWAP(k1, k2)
            #undef CSWAP
            #pragma unroll
            for (int rr = 0; rr < 8; ++rr) {
                u64 w = k0;
                #pragma unroll
                for (int off = 32; off >= 1; off >>= 1) {
                    u64 o = __shfl_xor(w, off);
                    if (o > w) w = o;
                }
                if (k0 == w) { k0 = k1; k1 = k2; k2 = k3; k3 = 0; }
                fbin[rr] = 256 - (int)(w & 0xff);
                cmag[rr] = __uint_as_float((unsigned)(w >> 32));
            }
        }
        if (lane == 0) {
            #pragma unroll
            for (int rr = 0; rr < 8; ++rr) fin8s[r][rr] = fbin[rr];
        }

        // gap check: fp32 ranking provably exact? (uniform across wave)
        const bool needRefine =
            ((cmag[0] - cmag[1]) <= 1e-4f * cmag[0]) || ((cmag[1] - cmag[2]) <= 1e-4f * cmag[1]) ||
            ((cmag[2] - cmag[3]) <= 1e-4f * cmag[2]) || ((cmag[3] - cmag[4]) <= 1e-4f * cmag[3]);

        int bins[KP];
        if (!needRefine) {
            #pragma unroll
            for (int k = 0; k < KP; ++k) bins[k] = fbin[k];
        } else {
            // f64 refine: 8 candidates x 8 lanes, 64 samples per lane
            {
                const int cid = lane >> 3;
                const int sub = lane & 7;
                const int fc  = fin8s[r][cid];
                const int t0  = sub * 64;
                const double W = 6.2831853071795864769 / 512.0;
                double zr, zi, wr, wi;
                sincos(W * (double)((fc * t0) & 511), &zi, &zr);
                sincos(W * (double)fc, &wi, &wr);
                double ar = 0.0, ai = 0.0;
                const float4* r4 = (const float4*)rowl[r];
                #pragma unroll
                for (int v4i = 0; v4i < 16; ++v4i) {
                    float4 xv = r4[sub * 16 + v4i];
                    #define STEP(comp)                                   \
                        { double xd = (double)xv.comp;                   \
                          ar = fma(xd, zr, ar); ai = fma(xd, zi, ai);    \
                          double tq = zr * wr - zi * wi;                 \
                          zi = fma(zr, wi, zi * wr); zr = tq; }
                    STEP(x) STEP(y) STEP(z) STEP(w)
                    #undef STEP
                }
                #pragma unroll
                for (int off = 4; off >= 1; off >>= 1) {
                    ar += __shfl_xor(ar, off);
                    ai += __shfl_xor(ai, off);
                }
                if (sub == 0) candV8[r][cid] = ar * ar + ai * ai;
            }
            // serial exact select over 8 candidates (tie -> lower bin)
            unsigned chosen = 0;
            #pragma unroll
            for (int k = 0; k < KP; ++k) {
                double bv = -1.0; int bbin = 0x7fffffff; int bj = 0;
                #pragma unroll
                for (int j = 0; j < 8; ++j) {
                    if (chosen & (1u << j)) continue;
                    double vj = candV8[r][j];
                    int    bjn = fbin[j];
                    if (vj > bv || (vj == bv && bjn < bbin)) { bv = vj; bbin = bjn; bj = j; }
                }
                chosen |= (1u << bj);
                bins[k] = bbin;
            }
        }

        // params: publish to LDS for store team + write to global out
        int per[KP], cycv[KP], stv[KP];
        #pragma unroll
        for (int k = 0; k < KP; ++k) {
            int p = TT / bins[k];
            p = p < 8 ? 8 : (p > 64 ? 64 : p);
            per[k]  = p;
            cycv[k] = TT / p;
            stv[k]  = TT - cycv[k] * p;
        }
        if (lane == 0) {
            #pragma unroll
            for (int k = 0; k < KP; ++k) {
                pstore[r][k]     = per[k];
                pstore[r][4 + k] = cycv[k];
                pstore[r][8 + k] = stv[k];
                out[VOFF + (size_t)bn * KP + k]        = (float)per[k];
                out[VOFF + 8192 + (size_t)bn * KP + k] = (float)cycv[k];
            }
        }
        SYNCL();   // barrier 2: rowl/pstore visible to store team
    } else {
        // ================= store team: wave owns row r = wid-4 =================
        const int r  = wid - 4;
        const int bn = blk * 4 + r;
        float* outv = out + (size_t)bn * (KP * 64 * 64);
        const int cr = lane >> 4;     // 0..3: c-row within group
        const int j  = lane & 15;     // float4 column
        const float4 z = make_float4(0.f, 0.f, 0.f, 0.f);

        // s0: universally-zero region (c >= 8, j >= W4(c)) — flows from t~0
        #pragma unroll
        for (int c0 = 8; c0 < 64; c0 += 4) {
            const int c = c0 + cr;
            int W = 512 / (c + 1);
            W = W < 8 ? 8 : W;                  // c>=8 -> W<=56, no upper clamp needed
            const int W4c = (W + 3) >> 2;
            if (j >= W4c) {
                #pragma unroll
                for (int k = 0; k < KP; ++k)
                    *(float4*)(outv + k * 4096 + c * 64 + j * 4) = z;
            }
        }
        SYNCL();   // barrier 2: rowl[r]/pstore[r] ready

        // s1: possible-nonzero region (j < W4(c)): gather from LDS row + store
        int P[KP], C[KP], S0[KP];
        #pragma unroll
        for (int k = 0; k < KP; ++k) {
            P[k]  = pstore[r][k];
            C[k]  = pstore[r][4 + k];
            S0[k] = pstore[r][8 + k];
        }
        #pragma unroll
        for (int c0 = 0; c0 < 64; c0 += 4) {
            const int c = c0 + cr;
            int W = 512 / (c + 1);
            W = W < 8 ? 8 : (W > 64 ? 64 : W);
            const int W4c = (W + 3) >> 2;
            if (j < W4c) {
                const int p0 = j << 2;
                #pragma unroll
                for (int k = 0; k < KP; ++k) {
                    float4 vv = z;
                    if (c < C[k]) {
                        const int base = S0[k] + c * P[k] + p0;
                        if (p0 + 3 < P[k]) {
                            vv.x = rowl[r][base];
                            vv.y = rowl[r][base + 1];
                            vv.z = rowl[r][base + 2];
                            vv.w = rowl[r][base + 3];
                        } else {
                            if (p0     < P[k]) vv.x = rowl[r][base];
                            if (p0 + 1 < P[k]) vv.y = rowl[r][base + 1];
                            if (p0 + 2 < P[k]) vv.z = rowl[r][base + 2];
                            if (p0 + 3 < P[k]) vv.w = rowl[r][base + 3];
                        }
                    }
                    *(float4*)(outv + k * 4096 + c * 64 + p0) = vv;
                }
            }
        }
    }
}

extern "C" void kernel_launch(void* const* d_in, const int* in_sizes, int n_in,
                              void* d_out, int out_size, void* d_ws, size_t ws_size,
                              hipStream_t stream) {
    const float* x = (const float*)d_in[0];
    float* out = (float*)d_out;
    hipLaunchKernelGGL(periodicity_kernel, dim3(512), dim3(512), 0, stream, x, out);
}

// Round 9
// 30.470 us; speedup vs baseline: 1.2854x; 1.2854x over previous
//
#include <hip/hip_runtime.h>
#include <math.h>

#define TT 512
#define KP 4

typedef unsigned long long u64;

// LDS-only barrier: waits DS ops, leaves global memory ops unfenced.
#define SYNCL() asm volatile("s_waitcnt lgkmcnt(0)\n\ts_barrier" ::: "memory")

// one block per sequence row (bn = b*64 + n). 256 threads = 4 waves.
__global__ __launch_bounds__(256) void periodicity_kernel(const float* __restrict__ x,
                                                          float* __restrict__ out) {
    const int bn   = blockIdx.x;     // 0..2047
    const int tid  = threadIdx.x;    // 0..255
    const int lane = tid & 63;
    const int wid  = tid >> 6;
    const int b = bn >> 6;
    const int n = bn & 63;

    __shared__ float2 tw[TT];                       // tw[m] = e^{-2*pi*i*m/512}
    __shared__ __align__(16) float row[TT];         // natural order
    __shared__ float2 buf[TT];                      // FFT working buffer
    __shared__ u64    keys[256];                    // (mag_bits<<32)|(255-(f-1))
    __shared__ int    fin8[8];
    __shared__ float  candMagF[8];
    __shared__ double candV8[8];

    // ---- twiddles (one sincosf/thread) ----
    float sv, cv;
    sincosf((float)(2.0 * M_PI / 512.0) * (float)tid, &sv, &cv);
    tw[tid]       = make_float2(cv, -sv);
    tw[tid + 256] = make_float2(-cv, sv);

    // ---- load row (stride-64 column) + folded radix-2 first DIF stage ----
    const float* xb = x + (size_t)b * (TT * 64) + n;
    {
        float v0 = xb[(size_t)tid * 64];
        float v1 = xb[(size_t)(tid + 256) * 64];
        row[tid] = v0;  row[tid + 256] = v1;
        float sum = v0 + v1, dif = v0 - v1;
        buf[tid]       = make_float2(sum, 0.f);
        buf[tid + 256] = make_float2(dif * cv, -dif * sv);
    }
    SYNCL();

    // ---- radix-4 DIF stages 0..2 on the two 256-halves (128 active threads) ----
    #pragma unroll
    for (int stg = 0; stg < 3; ++stg) {
        if (tid < 128) {
            const int Q  = 64 >> (2 * stg);          // 64,16,4
            const int B4 = Q << 2;
            const int h  = tid >> 6;
            const int fj = tid & 63;
            const int g  = fj >> (6 - 2 * stg);
            const int i  = fj & (Q - 1);
            float2* bb = &buf[h << 8];
            const int base = g * B4 + i;
            float2 x0 = bb[base],         x1 = bb[base + Q];
            float2 x2 = bb[base + 2 * Q], x3 = bb[base + 3 * Q];
            float2 A  = make_float2(x0.x + x2.x, x0.y + x2.y);
            float2 Bm = make_float2(x0.x - x2.x, x0.y - x2.y);
            float2 Cc = make_float2(x1.x + x3.x, x1.y + x3.y);
            float2 D  = make_float2(x1.x - x3.x, x1.y - x3.y);
            float2 y0 = make_float2(A.x + Cc.x, A.y + Cc.y);
            float2 y2 = make_float2(A.x - Cc.x, A.y - Cc.y);
            float2 y1 = make_float2(Bm.x + D.y, Bm.y - D.x);   // Bm - i*D
            float2 y3 = make_float2(Bm.x - D.y, Bm.y + D.x);   // Bm + i*D
            const int m = i << (1 + 2 * stg);
            float2 t1 = tw[m], t2 = tw[2 * m], t3 = tw[3 * m];
            bb[base]         = y0;
            bb[base + Q]     = make_float2(y1.x * t1.x - y1.y * t1.y, y1.x * t1.y + y1.y * t1.x);
            bb[base + 2 * Q] = make_float2(y2.x * t2.x - y2.y * t2.y, y2.x * t2.y + y2.y * t2.x);
            bb[base + 3 * Q] = make_float2(y3.x * t3.x - y3.y * t3.y, y3.x * t3.y + y3.y * t3.x);
        }
        SYNCL();
    }

    // ---- stage 3 (Q=1, twiddles = 1) fused with mag^2 + key write ----
    // thread (h, g) produces bins f = 2*revg + h + 128*j for j=0..3
    if (tid < 128) {
        const int h = tid >> 6;
        const int g = tid & 63;
        float2* bb = &buf[h << 8];
        const int base = g << 2;
        float2 x0 = bb[base],     x1 = bb[base + 1];
        float2 x2 = bb[base + 2], x3 = bb[base + 3];
        float2 A  = make_float2(x0.x + x2.x, x0.y + x2.y);
        float2 Bm = make_float2(x0.x - x2.x, x0.y - x2.y);
        float2 Cc = make_float2(x1.x + x3.x, x1.y + x3.y);
        float2 D  = make_float2(x1.x - x3.x, x1.y - x3.y);
        float2 y0 = make_float2(A.x + Cc.x, A.y + Cc.y);
        float2 y2 = make_float2(A.x - Cc.x, A.y - Cc.y);
        float2 y1 = make_float2(Bm.x + D.y, Bm.y - D.x);   // Bm - i*D
        float2 y3 = make_float2(Bm.x - D.y, Bm.y + D.x);   // Bm + i*D
        const int revg = ((g & 3) << 4) | (((g >> 2) & 3) << 2) | ((g >> 4) & 3);
        const int f0 = 2 * revg + h;
        float mags[4];
        mags[0] = y0.x * y0.x + y0.y * y0.y;
        mags[1] = y1.x * y1.x + y1.y * y1.y;
        mags[2] = y2.x * y2.x + y2.y * y2.y;
        mags[3] = y3.x * y3.x + y3.y * y3.y;
        #pragma unroll
        for (int j = 0; j < 4; ++j) {
            const int f = f0 + 128 * j;
            if (f >= 1 && f <= 256)
                keys[f - 1] = ((u64)__float_as_uint(mags[j]) << 32) | (u64)(255 - (f - 1));
        }
    }
    SYNCL();

    // ---- top-8 of 256 keys (wave 0; value desc, bin asc) ----
    if (wid == 0) {
        u64 k0 = keys[lane * 4 + 0];
        u64 k1 = keys[lane * 4 + 1];
        u64 k2 = keys[lane * 4 + 2];
        u64 k3 = keys[lane * 4 + 3];
        #define CSWAP(a, b) { if (a < b) { u64 _t = a; a = b; b = _t; } }
        CSWAP(k0, k1) CSWAP(k2, k3) CSWAP(k0, k2) CSWAP(k1, k3) CSWAP(k1, k2)
        #undef CSWAP
        #pragma unroll
        for (int r = 0; r < 8; ++r) {
            u64 w = k0;
            #pragma unroll
            for (int off = 32; off >= 1; off >>= 1) {
                u64 o = __shfl_xor(w, off);
                if (o > w) w = o;
            }
            if (k0 == w) { k0 = k1; k1 = k2; k2 = k3; k3 = 0; }
            if (lane == 0) {
                fin8[r] = 256 - (int)(w & 0xff);
                candMagF[r] = __uint_as_float((unsigned)(w >> 32));
            }
        }
    }
    SYNCL();

    // ---- gap check: is the fp32 ranking provably exact? (uniform branch) ----
    int per[KP], cycv[KP], stv[KP];
    {
        const float m0 = candMagF[0], m1 = candMagF[1], m2 = candMagF[2],
                    m3 = candMagF[3], m4 = candMagF[4];
        const bool needRefine = ((m0 - m1) <= 1e-4f * m0) || ((m1 - m2) <= 1e-4f * m1) ||
                                ((m2 - m3) <= 1e-4f * m2) || ((m3 - m4) <= 1e-4f * m3);
        int bins[KP];
        if (!needRefine) {
            #pragma unroll
            for (int k = 0; k < KP; ++k) bins[k] = fin8[k];
        } else {
            // ---- f64 refine of the 8 candidates (rare; exact ranking) ----
            {
                const int cid = tid >> 5;
                const int sub = tid & 31;
                const int fc  = fin8[cid];
                const int t0  = sub * 16;
                const double W = 6.2831853071795864769 / 512.0;
                double zr, zi, wr, wi;
                sincos(W * (double)((fc * t0) & 511), &zi, &zr);
                sincos(W * (double)fc, &wi, &wr);
                double ar = 0.0, ai = 0.0;
                const float4* r4 = (const float4*)row;
                #pragma unroll
                for (int v4i = 0; v4i < 4; ++v4i) {
                    float4 xv = r4[sub * 4 + v4i];
                    #define STEP(comp)                                   \
                        { double xd = (double)xv.comp;                   \
                          ar = fma(xd, zr, ar); ai = fma(xd, zi, ai);    \
                          double tq = zr * wr - zi * wi;                 \
                          zi = fma(zr, wi, zi * wr); zr = tq; }
                    STEP(x) STEP(y) STEP(z) STEP(w)
                    #undef STEP
                }
                #pragma unroll
                for (int off = 16; off >= 1; off >>= 1) {
                    ar += __shfl_xor(ar, off);
                    ai += __shfl_xor(ai, off);
                }
                if (sub == 0) candV8[cid] = ar * ar + ai * ai;
            }
            SYNCL();
            unsigned chosen = 0;
            #pragma unroll
            for (int k = 0; k < KP; ++k) {
                double bv = -1.0; int bbin = 0x7fffffff; int bj = 0;
                #pragma unroll
                for (int j = 0; j < 8; ++j) {
                    if (chosen & (1u << j)) continue;
                    double vj = candV8[j];
                    int    bjn = fin8[j];
                    if (vj > bv || (vj == bv && bjn < bbin)) { bv = vj; bbin = bjn; bj = j; }
                }
                chosen |= (1u << bj);
                bins[k] = bbin;
            }
        }
        #pragma unroll
        for (int k = 0; k < KP; ++k) {
            int p = TT / bins[k];
            p = p < 8 ? 8 : (p > 64 ? 64 : p);
            per[k]  = p;
            cycv[k] = TT / p;
            stv[k]  = TT - cycv[k] * p;
        }
    }

    const size_t VOFF = (size_t)2048 * KP * 64 * 64;   // 33,554,432
    if (tid == 0) {
        #pragma unroll
        for (int k = 0; k < KP; ++k) {
            out[VOFF + (size_t)bn * KP + k]        = (float)per[k];
            out[VOFF + 8192 + (size_t)bn * KP + k] = (float)cycv[k];
        }
    }

    // ---- gather + vectorized dense store: values[bn, k, c, p] (R4 verbatim) ----
    float* outv = out + (size_t)bn * (KP * 64 * 64);
    const int c_local = tid >> 4;
    const int p0 = (tid & 15) << 2;
    #pragma unroll
    for (int it = 0; it < 16; ++it) {
        const int k = it >> 2;
        const int c = ((it & 3) << 4) + c_local;
        float4 v = make_float4(0.f, 0.f, 0.f, 0.f);
        const int P = per[k], C = cycv[k], S0 = stv[k];
        if (c < C) {
            const int base = S0 + c * P;
            if (p0 + 3 < P) {
                v.x = row[base + p0];
                v.y = row[base + p0 + 1];
                v.z = row[base + p0 + 2];
                v.w = row[base + p0 + 3];
            } else {
                if (p0     < P) v.x = row[base + p0];
                if (p0 + 1 < P) v.y = row[base + p0 + 1];
                if (p0 + 2 < P) v.z = row[base + p0 + 2];
                if (p0 + 3 < P) v.w = row[base + p0 + 3];
            }
        }
        *(float4*)(outv + (size_t)it * 1024 + (size_t)tid * 4) = v;
    }
}

extern "C" void kernel_launch(void* const* d_in, const int* in_sizes, int n_in,
                              void* d_out, int out_size, void* d_ws, size_t ws_size,
                              hipStream_t stream) {
    const float* x = (const float*)d_in[0];
    float* out = (float*)d_out;
    hipLaunchKernelGGL(periodicity_kernel, dim3(2048), dim3(256), 0, stream, x, out);
}